// Round 3
// baseline (36976.816 us; speedup 1.0000x reference)
//
#include <hip/hip_runtime.h>
#include <cstdint>

#define HID 256
#define NG 1024
#define TT 256
#define WIN 128
#define K0 264
#define K1 512
#define OUTW 129
#define NCLUS 8     // clusters (one per XCD)
#define CPC 32      // CUs (blocks) per cluster
#define RPC 128     // batch rows per cluster
#define NTHR 512

// ---- workspace layout (float offsets, contiguous) ----
#define OFF_WT0 0
#define SZ_WT0 (K0*NG)
#define OFF_WT1 (OFF_WT0+SZ_WT0)
#define SZ_WT1 (K1*NG)
#define OFF_BS0 (OFF_WT1+SZ_WT1)
#define OFF_BS1 (OFF_BS0+NG)
#define OFF_H0  (OFF_BS1+NG)
#define SZ_H    (NCLUS*2*HID*RPC)
#define OFF_H1  (OFF_H0+SZ_H)
#define OFF_CTR (OFF_H1+SZ_H)
#define WS_FLOATS (OFF_CTR+64)

// ---- LDS layout (float offsets) ----
#define L_WL0  0
#define L_WL1  (L_WL0 + K0*36)     // 9504
#define L_GL   (L_WL1 + K1*36)     // 27936
#define L_XIN  (L_GL + RPC*36)     // 32544
#define L_WLIN (L_XIN + 8*132)     // 33600
#define L_BS0  (L_WLIN + HID)      // 33856
#define L_BS1  (L_BS0 + 32)        // 33888
#define SMEM_FLOATS (L_BS1 + 32)   // 33920
#define SMEM_BYTES  (SMEM_FLOATS*4)

__device__ __forceinline__ float sigm(float z)  { return 1.0f / (1.0f + __expf(-z)); }
__device__ __forceinline__ float tanhx(float z) { float e = __expf(2.0f * z); return 1.0f - 2.0f / (e + 1.0f); }

#define FMA4(A, W, S) { (A).x = fmaf((W).x,(S),(A).x); (A).y = fmaf((W).y,(S),(A).y); \
                        (A).z = fmaf((W).z,(S),(A).z); (A).w = fmaf((W).w,(S),(A).w); }

// ---------------------------------------------------------------------------
// prep: k-major weight panels + fused biases; zero h-broadcast bufs + counters
// ---------------------------------------------------------------------------
__global__ void prep_kernel(const float* __restrict__ Wih0, const float* __restrict__ Whh0,
                            const float* __restrict__ bih0, const float* __restrict__ bhh0,
                            const float* __restrict__ Wih1, const float* __restrict__ Whh1,
                            const float* __restrict__ bih1, const float* __restrict__ bhh1,
                            float* __restrict__ ws, int full) {
  const int n0 = K0 * NG, n1 = K1 * NG;
  const int total = full ? WS_FLOATS : (n0 + n1 + 2 * NG);
  for (int i = blockIdx.x * blockDim.x + threadIdx.x; i < total; i += gridDim.x * blockDim.x) {
    float v;
    if (i < n0) {
      int k = i >> 10, g = i & (NG - 1);
      v = (k < 8) ? Wih0[g * 8 + k] : Whh0[g * HID + (k - 8)];
    } else if (i < n0 + n1) {
      int j = i - n0;
      int k = j >> 10, g = j & (NG - 1);
      v = (k < HID) ? Wih1[g * HID + k] : Whh1[g * HID + (k - HID)];
    } else if (i < n0 + n1 + NG) {
      int g = i - n0 - n1;
      v = bih0[g] + bhh0[g];
    } else if (i < n0 + n1 + 2 * NG) {
      int g = i - n0 - n1 - NG;
      v = bih1[g] + bhh1[g];
    } else {
      v = 0.0f;      // h buffers (both parities) + barrier counters
    }
    ws[i] = v;
  }
}

// ---------------------------------------------------------------------------
// cluster kernel helpers
// ---------------------------------------------------------------------------
__device__ __forceinline__ void reduce_store(float4 (&acc)[8], float* sGl, int rb, int g4, int ksl) {
  #pragma unroll
  for (int m = 0; m < 8; ++m) {
    acc[m].x += __shfl_xor(acc[m].x, 16); acc[m].x += __shfl_xor(acc[m].x, 32);
    acc[m].y += __shfl_xor(acc[m].y, 16); acc[m].y += __shfl_xor(acc[m].y, 32);
    acc[m].z += __shfl_xor(acc[m].z, 16); acc[m].z += __shfl_xor(acc[m].z, 32);
    acc[m].w += __shfl_xor(acc[m].w, 16); acc[m].w += __shfl_xor(acc[m].w, 32);
  }
  if (ksl == 0) {
    #pragma unroll
    for (int m = 0; m < 8; ++m) *(float4*)&sGl[(rb + m) * 36 + (g4 << 2)] = acc[m];
  }
}

__device__ __forceinline__ void epilogue(const float* sGl, const float* sBs, float (&cst)[2],
                                         float* hdst, int jl, int rr) {
  #pragma unroll
  for (int q = 0; q < 2; ++q) {
    const int r = (rr << 1) + q;
    const float gi = sGl[r * 36 +      jl] + sBs[jl];
    const float gf = sGl[r * 36 +  8 + jl] + sBs[8 + jl];
    const float gg = sGl[r * 36 + 16 + jl] + sBs[16 + jl];
    const float go = sGl[r * 36 + 24 + jl] + sBs[24 + jl];
    float c = sigm(gf) * cst[q] + sigm(gi) * tanhx(gg);
    cst[q] = c;
    hdst[r] = sigm(go) * tanhx(c);
  }
}

__device__ __forceinline__ void cluster_barrier(unsigned int* ctr, unsigned int target) {
  __threadfence();                 // make this thread's global stores agent-visible
  __syncthreads();
  if (threadIdx.x == 0) {
    __hip_atomic_fetch_add(ctr, 1u, __ATOMIC_RELEASE, __HIP_MEMORY_SCOPE_AGENT);
    while (__hip_atomic_load(ctr, __ATOMIC_RELAXED, __HIP_MEMORY_SCOPE_AGENT) < target)
      __builtin_amdgcn_s_sleep(4);
  }
  __syncthreads();
  // per-thread agent-scope acquire -> invalidate caches before reading peers' data
  (void)__hip_atomic_load(ctr, __ATOMIC_ACQUIRE, __HIP_MEMORY_SCOPE_AGENT);
}

// ---------------------------------------------------------------------------
// Cooperative cluster kernel: 256 blocks x 512 threads, 1 block/CU (LDS-bound).
// cluster = blockIdx&7 (XCD), cu = blockIdx>>3 owns hidden units [8cu, 8cu+8).
// ---------------------------------------------------------------------------
__global__ __launch_bounds__(NTHR) void lstm_cluster(
    const float* __restrict__ x, const float* __restrict__ Wlin,
    const float* __restrict__ blin, float* __restrict__ ws,
    float* __restrict__ out)
{
  extern __shared__ float sm[];
  float* sWL0  = sm + L_WL0;
  float* sWL1  = sm + L_WL1;
  float* sGl   = sm + L_GL;
  float* sXin  = sm + L_XIN;
  float* sWlin = sm + L_WLIN;
  float* sBs0  = sm + L_BS0;
  float* sBs1  = sm + L_BS1;

  const int clus = blockIdx.x & 7;
  const int cu   = blockIdx.x >> 3;
  const int tid  = threadIdx.x;
  const int lane = tid & 63;
  const int wave = tid >> 6;
  const int ksl  = lane >> 4;            // k-slice 0..3 (k = 4i + ksl)
  const int t16  = lane & 15;
  const int tile = wave * 16 + t16;      // 0..127
  const int g4   = tile & 7;             // gate quad (gates 4*g4..+3 of 32)
  const int rb   = (tile >> 3) * 8;      // row base (8 rows per tile)
  const int jl   = tid & 7;              // epilogue hidden-unit lane
  const int rr   = tid >> 3;             // epilogue row-pair 0..63
  const int kc   = tid & 3;              // pred k-chunk
  const int rp   = tid >> 2;             // pred row 0..127
  unsigned int* ctr = (unsigned int*)(ws + OFF_CTR) + clus;

  // ---- one-time: stage this CU's weight slice + bias + Wlin into LDS ----
  for (int idx = tid; idx < K0 * 32; idx += NTHR) {
    int k = idx >> 5, g = idx & 31;     // g = gatetype*8 + jl
    sWL0[k * 36 + g] = ws[OFF_WT0 + k * NG + (g >> 3) * HID + cu * 8 + (g & 7)];
  }
  for (int idx = tid; idx < K1 * 32; idx += NTHR) {
    int k = idx >> 5, g = idx & 31;
    sWL1[k * 36 + g] = ws[OFF_WT1 + k * NG + (g >> 3) * HID + cu * 8 + (g & 7)];
  }
  if (tid < HID) sWlin[tid] = Wlin[tid];
  if (tid < 32) {
    sBs0[tid] = ws[OFF_BS0 + (tid >> 3) * HID + cu * 8 + (tid & 7)];
    sBs1[tid] = ws[OFF_BS1 + (tid >> 3) * HID + cu * 8 + (tid & 7)];
  }
  const float blv = blin[0];
  float c0q[2] = {0.f, 0.f}, c1q[2] = {0.f, 0.f};
  unsigned int barSeq = 0;
  __syncthreads();

  for (int t = 0; t < TT; ++t) {
    const int p = t & 1;
    float* h0prev = ws + OFF_H0 + (size_t)(clus * 2 + p) * HID * RPC;
    float* h0new  = ws + OFF_H0 + (size_t)(clus * 2 + (p ^ 1)) * HID * RPC;
    float* h1prev = ws + OFF_H1 + (size_t)(clus * 2 + p) * HID * RPC;
    float* h1new  = ws + OFF_H1 + (size_t)(clus * 2 + (p ^ 1)) * HID * RPC;

    // ---- A: stage x features into LDS (feat0 only during warmup) ----
    {
      const int f = tid & 7;
      #pragma unroll
      for (int q = 0; q < 2; ++q) {
        const int r = ((tid >> 3) << 1) + q;
        if (f > 0 || t < WIN)
          sXin[f * 132 + r] = x[((size_t)(clus * RPC + r) * TT + t) * 8 + f];
      }
    }
    // ---- A2: prediction from h1(t-1); feeds xin[0] and output col t-WIN ----
    if (t >= WIN) {
      float s0 = 0.f, s1 = 0.f, s2 = 0.f, s3 = 0.f;
      const float* hp = h1prev + rp;
      #pragma unroll 4
      for (int i = 0; i < 64; i += 4) {
        const int k = (kc << 6) + i;
        s0 = fmaf(sWlin[k],     hp[(size_t)k * RPC],            s0);
        s1 = fmaf(sWlin[k + 1], hp[(size_t)(k + 1) * RPC],      s1);
        s2 = fmaf(sWlin[k + 2], hp[(size_t)(k + 2) * RPC],      s2);
        s3 = fmaf(sWlin[k + 3], hp[(size_t)(k + 3) * RPC],      s3);
      }
      float s = (s0 + s1) + (s2 + s3);
      s += __shfl_xor(s, 1);
      s += __shfl_xor(s, 2);
      if (kc == 0) {
        const float pv = s + blv;
        sXin[rp] = pv;
        if (cu == 0) out[(size_t)(clus * RPC + rp) * OUTW + (t - WIN)] = pv;
      }
    }
    __syncthreads();

    // ---- B: layer-0 gates (32 gates x 128 rows, k-split x4 in-wave) ----
    {
      float4 acc[8];
      #pragma unroll
      for (int m = 0; m < 8; ++m) acc[m] = make_float4(0.f, 0.f, 0.f, 0.f);
      #pragma unroll
      for (int i = 0; i < 2; ++i) {          // k in [0,8): x inputs (LDS)
        const int k = (i << 2) + ksl;
        const float4 w  = *(const float4*)&sWL0[k * 36 + (g4 << 2)];
        const float4 ha = *(const float4*)&sXin[k * 132 + rb];
        const float4 hb = *(const float4*)&sXin[k * 132 + rb + 4];
        FMA4(acc[0], w, ha.x); FMA4(acc[1], w, ha.y); FMA4(acc[2], w, ha.z); FMA4(acc[3], w, ha.w);
        FMA4(acc[4], w, hb.x); FMA4(acc[5], w, hb.y); FMA4(acc[6], w, hb.z); FMA4(acc[7], w, hb.w);
      }
      #pragma unroll 4
      for (int i = 2; i < 66; ++i) {         // k in [8,264): h0_prev (L2 broadcast)
        const int k = (i << 2) + ksl;
        const float4 w  = *(const float4*)&sWL0[k * 36 + (g4 << 2)];
        const float* hp = h0prev + (size_t)(k - 8) * RPC + rb;
        const float4 ha = *(const float4*)hp;
        const float4 hb = *(const float4*)(hp + 4);
        FMA4(acc[0], w, ha.x); FMA4(acc[1], w, ha.y); FMA4(acc[2], w, ha.z); FMA4(acc[3], w, ha.w);
        FMA4(acc[4], w, hb.x); FMA4(acc[5], w, hb.y); FMA4(acc[6], w, hb.z); FMA4(acc[7], w, hb.w);
      }
      reduce_store(acc, sGl, rb, g4, ksl);
    }
    __syncthreads();

    // ---- D: epilogue 0 -> h0_new slice to global ----
    epilogue(sGl, sBs0, c0q, h0new + (size_t)(cu * 8 + jl) * RPC, jl, rr);
    cluster_barrier(ctr, CPC * (++barSeq));

    // ---- E: layer-1 gates ----
    {
      float4 acc[8];
      #pragma unroll
      for (int m = 0; m < 8; ++m) acc[m] = make_float4(0.f, 0.f, 0.f, 0.f);
      #pragma unroll 4
      for (int i = 0; i < 64; ++i) {         // k in [0,256): h0_new
        const int k = (i << 2) + ksl;
        const float4 w  = *(const float4*)&sWL1[k * 36 + (g4 << 2)];
        const float* hp = h0new + (size_t)k * RPC + rb;
        const float4 ha = *(const float4*)hp;
        const float4 hb = *(const float4*)(hp + 4);
        FMA4(acc[0], w, ha.x); FMA4(acc[1], w, ha.y); FMA4(acc[2], w, ha.z); FMA4(acc[3], w, ha.w);
        FMA4(acc[4], w, hb.x); FMA4(acc[5], w, hb.y); FMA4(acc[6], w, hb.z); FMA4(acc[7], w, hb.w);
      }
      #pragma unroll 4
      for (int i = 64; i < 128; ++i) {       // k in [256,512): h1_prev
        const int k = (i << 2) + ksl;
        const float4 w  = *(const float4*)&sWL1[k * 36 + (g4 << 2)];
        const float* hp = h1prev + (size_t)(k - 256) * RPC + rb;
        const float4 ha = *(const float4*)hp;
        const float4 hb = *(const float4*)(hp + 4);
        FMA4(acc[0], w, ha.x); FMA4(acc[1], w, ha.y); FMA4(acc[2], w, ha.z); FMA4(acc[3], w, ha.w);
        FMA4(acc[4], w, hb.x); FMA4(acc[5], w, hb.y); FMA4(acc[6], w, hb.z); FMA4(acc[7], w, hb.w);
      }
      reduce_store(acc, sGl, rb, g4, ksl);
    }
    __syncthreads();

    // ---- G: epilogue 1 -> h1_new slice to global ----
    epilogue(sGl, sBs1, c1q, h1new + (size_t)(cu * 8 + jl) * RPC, jl, rr);
    cluster_barrier(ctr, CPC * (++barSeq));
  }

  // ---- final prediction (from h1 after step 255, parity 0) -> col 128 ----
  if (cu == 0) {
    const float* h1f = ws + OFF_H1 + (size_t)(clus * 2 + 0) * HID * RPC;
    float s0 = 0.f, s1 = 0.f, s2 = 0.f, s3 = 0.f;
    const float* hp = h1f + rp;
    #pragma unroll 4
    for (int i = 0; i < 64; i += 4) {
      const int k = (kc << 6) + i;
      s0 = fmaf(sWlin[k],     hp[(size_t)k * RPC],       s0);
      s1 = fmaf(sWlin[k + 1], hp[(size_t)(k + 1) * RPC], s1);
      s2 = fmaf(sWlin[k + 2], hp[(size_t)(k + 2) * RPC], s2);
      s3 = fmaf(sWlin[k + 3], hp[(size_t)(k + 3) * RPC], s3);
    }
    float s = (s0 + s1) + (s2 + s3);
    s += __shfl_xor(s, 1);
    s += __shfl_xor(s, 2);
    if (kc == 0) out[(size_t)(clus * RPC + rp) * OUTW + 128] = s + blv;
  }
}

// ---------------------------------------------------------------------------
// Fallback (round-1 kernel, proven): used only if ws_size is too small.
// ---------------------------------------------------------------------------
__global__ __launch_bounds__(256) void lstm_ar_kernel(
    const float* __restrict__ x, const float* __restrict__ Wlin,
    const float* __restrict__ blin, const float* __restrict__ ws,
    float* __restrict__ out)
{
  const float* WT0 = ws;
  const float* WT1 = ws + K0 * NG;
  const float* bs0 = ws + (K0 + K1) * NG;
  const float* bs1 = bs0 + NG;

  __shared__ float in0[K0][4];
  __shared__ float in1[K1][4];
  __shared__ float c0s[HID][4];
  __shared__ float c1s[HID][4];
  __shared__ float gl[4][NG];
  __shared__ float predl[4];

  const int tid = threadIdx.x;
  const int r0  = blockIdx.x << 2;

  {
    float4 z = make_float4(0.f, 0.f, 0.f, 0.f);
    *(float4*)&c0s[tid][0]       = z;
    *(float4*)&c1s[tid][0]       = z;
    *(float4*)&in0[8 + tid][0]   = z;
    *(float4*)&in1[tid][0]       = z;
    *(float4*)&in1[HID + tid][0] = z;
  }
  __syncthreads();

  for (int t = 0; t < TT; ++t) {
    if (tid < 32) {
      int r = tid >> 3, k = tid & 7;
      float v;
      if (t >= WIN && k == 0) v = predl[r];
      else v = x[((size_t)(r0 + r) * TT + t) * 8 + k];
      in0[k][r] = v;
    }
    __syncthreads();
    {
      const int g4 = tid << 2;
      float4 b = *(const float4*)&bs0[g4];
      float4 a0 = b, a1 = b, a2 = b, a3 = b;
      #pragma unroll 4
      for (int k = 0; k < K0; ++k) {
        const float4 w = *(const float4*)&WT0[(k << 10) + g4];
        const float4 h = *(const float4*)&in0[k][0];
        a0.x += w.x*h.x; a0.y += w.y*h.x; a0.z += w.z*h.x; a0.w += w.w*h.x;
        a1.x += w.x*h.y; a1.y += w.y*h.y; a1.z += w.z*h.y; a1.w += w.w*h.y;
        a2.x += w.x*h.z; a2.y += w.y*h.z; a2.z += w.z*h.z; a2.w += w.w*h.z;
        a3.x += w.x*h.w; a3.y += w.y*h.w; a3.z += w.z*h.w; a3.w += w.w*h.w;
      }
      *(float4*)&gl[0][g4] = a0; *(float4*)&gl[1][g4] = a1;
      *(float4*)&gl[2][g4] = a2; *(float4*)&gl[3][g4] = a3;
    }
    __syncthreads();
    {
      const int j = tid;
      float4 c = *(const float4*)&c0s[j][0];
      float cc[4] = {c.x, c.y, c.z, c.w};
      float hh[4];
      #pragma unroll
      for (int r = 0; r < 4; ++r) {
        float ig = sigm(gl[r][j]);
        float fg = sigm(gl[r][HID + j]);
        float gg = tanhx(gl[r][2 * HID + j]);
        float og = sigm(gl[r][3 * HID + j]);
        float cn = fg * cc[r] + ig * gg;
        cc[r] = cn; hh[r] = og * tanhx(cn);
      }
      *(float4*)&c0s[j][0] = make_float4(cc[0], cc[1], cc[2], cc[3]);
      float4 hv = make_float4(hh[0], hh[1], hh[2], hh[3]);
      *(float4*)&in0[8 + j][0] = hv;
      *(float4*)&in1[j][0]     = hv;
    }
    __syncthreads();
    {
      const int g4 = tid << 2;
      float4 b = *(const float4*)&bs1[g4];
      float4 a0 = b, a1 = b, a2 = b, a3 = b;
      #pragma unroll 4
      for (int k = 0; k < K1; ++k) {
        const float4 w = *(const float4*)&WT1[(k << 10) + g4];
        const float4 h = *(const float4*)&in1[k][0];
        a0.x += w.x*h.x; a0.y += w.y*h.x; a0.z += w.z*h.x; a0.w += w.w*h.x;
        a1.x += w.x*h.y; a1.y += w.y*h.y; a1.z += w.z*h.y; a1.w += w.w*h.y;
        a2.x += w.x*h.z; a2.y += w.y*h.z; a2.z += w.z*h.z; a2.w += w.w*h.z;
        a3.x += w.x*h.w; a3.y += w.y*h.w; a3.z += w.z*h.w; a3.w += w.w*h.w;
      }
      *(float4*)&gl[0][g4] = a0; *(float4*)&gl[1][g4] = a1;
      *(float4*)&gl[2][g4] = a2; *(float4*)&gl[3][g4] = a3;
    }
    __syncthreads();
    {
      const int j = tid;
      float4 c = *(const float4*)&c1s[j][0];
      float cc[4] = {c.x, c.y, c.z, c.w};
      float hh[4];
      #pragma unroll
      for (int r = 0; r < 4; ++r) {
        float ig = sigm(gl[r][j]);
        float fg = sigm(gl[r][HID + j]);
        float gg = tanhx(gl[r][2 * HID + j]);
        float og = sigm(gl[r][3 * HID + j]);
        float cn = fg * cc[r] + ig * gg;
        cc[r] = cn; hh[r] = og * tanhx(cn);
      }
      *(float4*)&c1s[j][0] = make_float4(cc[0], cc[1], cc[2], cc[3]);
      *(float4*)&in1[HID + j][0] = make_float4(hh[0], hh[1], hh[2], hh[3]);
    }
    __syncthreads();
    if (t >= WIN - 1) {
      const int w = tid >> 6, l = tid & 63;
      float s = 0.f;
      #pragma unroll
      for (int q = 0; q < 4; ++q) {
        int j = l + (q << 6);
        s += Wlin[j] * in1[HID + j][w];
      }
      #pragma unroll
      for (int off = 32; off; off >>= 1) s += __shfl_down(s, off);
      if (l == 0) {
        float pv = s + blin[0];
        predl[w] = pv;
        out[(size_t)(r0 + w) * OUTW + (t - (WIN - 1))] = pv;
      }
    }
    __syncthreads();
  }
}

// ---------------------------------------------------------------------------
extern "C" void kernel_launch(void* const* d_in, const int* in_sizes, int n_in,
                              void* d_out, int out_size, void* d_ws, size_t ws_size,
                              hipStream_t stream) {
  (void)in_sizes; (void)n_in; (void)out_size;
  const float* x    = (const float*)d_in[0];
  const float* Wih0 = (const float*)d_in[1];
  const float* Whh0 = (const float*)d_in[2];
  const float* bih0 = (const float*)d_in[3];
  const float* bhh0 = (const float*)d_in[4];
  const float* Wih1 = (const float*)d_in[5];
  const float* Whh1 = (const float*)d_in[6];
  const float* bih1 = (const float*)d_in[7];
  const float* bhh1 = (const float*)d_in[8];
  const float* Wlin = (const float*)d_in[9];
  const float* blin = (const float*)d_in[10];
  float* ws  = (float*)d_ws;
  float* out = (float*)d_out;

  const int full = (ws_size >= (size_t)WS_FLOATS * sizeof(float)) ? 1 : 0;
  prep_kernel<<<1024, 256, 0, stream>>>(Wih0, Whh0, bih0, bhh0,
                                        Wih1, Whh1, bih1, bhh1, ws, full);
  if (full) {
    (void)hipFuncSetAttribute(reinterpret_cast<const void*>(lstm_cluster),
                              hipFuncAttributeMaxDynamicSharedMemorySize, SMEM_BYTES);
    const float* xp = x; const float* wl = Wlin; const float* bl = blin;
    float* wsp = ws; float* op = out;
    void* args[] = {(void*)&xp, (void*)&wl, (void*)&bl, (void*)&wsp, (void*)&op};
    (void)hipLaunchCooperativeKernel(reinterpret_cast<const void*>(lstm_cluster),
                                     dim3(NCLUS * CPC), dim3(NTHR), args, SMEM_BYTES, stream);
  } else {
    lstm_ar_kernel<<<256, 256, 0, stream>>>(x, Wlin, blin, ws, out);
  }
}

// Round 4
// 30598.566 us; speedup vs baseline: 1.2084x; 1.2084x over previous
//
#include <hip/hip_runtime.h>
#include <cstdint>

#define HID 256
#define NG 1024
#define TT 256
#define WIN 128
#define OUTW 129
#define NBLK 64
#define ROWS 16
#define NTHR 1024
#define KK0 9          // layer0 K = 288 (8 x + 256 h0 + 24 pad)
#define KK1 16         // layer1 K = 512 (256 h0 + 256 h1)
#define GLP 1044       // gate LDS row stride (floats), anti-bank-conflict

typedef _Float16 half8 __attribute__((ext_vector_type(8)));
typedef float f32x4 __attribute__((ext_vector_type(4)));

// packed weights: [kk][nt(64)][plane(2)][lane(64)][8 halves]; kk-stride = 65536 halves
#define W0H (KK0 * 65536)
#define W1H (KK1 * 65536)

__device__ __forceinline__ float sigm(float z)  { return 1.0f / (1.0f + __expf(-z)); }
__device__ __forceinline__ float tanhx(float z) { float e = __expf(2.0f * z); return 1.0f - 2.0f / (e + 1.0f); }

// exact hi/lo fp16 split; hi forced 0 below 2^-10 so both planes stay fp16-normal
// (lo plane carries a 2^11 scale, undone after MFMA accumulate)
__device__ __forceinline__ void split_f(float v, _Float16& hi, _Float16& lo) {
  float h = (fabsf(v) < 0.0009765625f) ? 0.0f : (float)(_Float16)v;
  hi = (_Float16)h;
  lo = (_Float16)((v - h) * 2048.0f);
}

// A-fragment LDS index for input-dim k, batch-row r (halves):
// lane l reads k = kk*32 + (l>>4)*8 + j at (kk*64 + l)*8 + j
__device__ __forceinline__ int aidx(int k, int r) {
  return ((k >> 5) * 64 + ((k >> 3) & 3) * 16 + r) * 8 + (k & 7);
}

// ---------------------------------------------------------------------------
// prep: pack weights into B-fragment order, fp16 hi/lo planes.
// B frag for mfma_f32_16x16x32_f16: lane l holds B[k=kk*32+(l>>4)*8+j][n=nt*16+(l&15)]
// ---------------------------------------------------------------------------
__global__ void prep_pack(const float* __restrict__ Wih0, const float* __restrict__ Whh0,
                          const float* __restrict__ Wih1, const float* __restrict__ Whh1,
                          _Float16* __restrict__ wp) {
  const int total = W0H + W1H;
  for (int i = blockIdx.x * blockDim.x + threadIdx.x; i < total; i += gridDim.x * blockDim.x) {
    int layer, kk, rem;
    if (i < W0H) { layer = 0; kk = i >> 16; rem = i & 65535; }
    else { int j = i - W0H; layer = 1; kk = j >> 16; rem = j & 65535; }
    const int nt    = rem >> 10;
    const int plane = (rem >> 9) & 1;
    const int lane  = (rem >> 3) & 63;
    const int j8    = rem & 7;
    const int k = kk * 32 + ((lane >> 4) << 3) + j8;
    const int n = nt * 16 + (lane & 15);
    float w;
    if (layer == 0) {
      if (k < 8)        w = Wih0[n * 8 + k];
      else if (k < 264) w = Whh0[n * 256 + (k - 8)];
      else              w = 0.0f;                       // K pad
    } else {
      if (k < 256)      w = Wih1[n * 256 + k];
      else              w = Whh1[n * 256 + (k - 256)];
    }
    _Float16 hi, lo; split_f(w, hi, lo);
    wp[i] = plane ? lo : hi;
  }
}

// ---------------------------------------------------------------------------
// per-wave gate GEMM: 16 rows x 64 gates (4 N-tiles), 3-product fp16 emulation
// ---------------------------------------------------------------------------
template<int KK>
__device__ __forceinline__ void gate_phase(const _Float16* __restrict__ wB,
                                           const _Float16* __restrict__ sAh,
                                           const _Float16* __restrict__ sAl,
                                           float* __restrict__ sGl,
                                           int wv, int lane) {
  f32x4 zz = {0.f, 0.f, 0.f, 0.f};
  f32x4 a0[4], a1[4], a2[4];
  #pragma unroll
  for (int i = 0; i < 4; ++i) { a0[i] = zz; a1[i] = zz; a2[i] = zz; }
  for (int kk = 0; kk < KK; ++kk) {
    const half8 ah = *(const half8*)(sAh + kk * 512 + lane * 8);
    const half8 al = *(const half8*)(sAl + kk * 512 + lane * 8);
    const _Float16* bp = wB + (size_t)kk * 65536 + (size_t)(wv * 4) * 1024 + lane * 8;
    #pragma unroll
    for (int i = 0; i < 4; ++i) {
      const half8 bh = *(const half8*)(bp + i * 1024);
      const half8 bl = *(const half8*)(bp + i * 1024 + 512);
      a0[i] = __builtin_amdgcn_mfma_f32_16x16x32_f16(ah, bh, a0[i], 0, 0, 0);
      a1[i] = __builtin_amdgcn_mfma_f32_16x16x32_f16(ah, bl, a1[i], 0, 0, 0);
      a2[i] = __builtin_amdgcn_mfma_f32_16x16x32_f16(al, bh, a2[i], 0, 0, 0);
    }
  }
  // D frag: col = lane&15, row = (lane>>4)*4 + r
  const int dr0 = (lane >> 4) << 2;
  const int dc  = lane & 15;
  #pragma unroll
  for (int i = 0; i < 4; ++i) {
    const int col = (wv * 4 + i) * 16 + dc;
    #pragma unroll
    for (int r = 0; r < 4; ++r)
      sGl[(dr0 + r) * GLP + col] = a0[i][r] + 4.8828125e-4f * (a1[i][r] + a2[i][r]);
  }
}

// ---------------------------------------------------------------------------
// main: 64 blocks x 1024 threads, 16 batch rows/block, zero inter-block traffic
// ---------------------------------------------------------------------------
__global__ __launch_bounds__(NTHR, 4) void lstm_mfma(
    const float* __restrict__ x,
    const float* __restrict__ bih0, const float* __restrict__ bhh0,
    const float* __restrict__ bih1, const float* __restrict__ bhh1,
    const float* __restrict__ Wlin, const float* __restrict__ blin,
    const _Float16* __restrict__ wp, float* __restrict__ out)
{
  extern __shared__ char smraw[];
  _Float16* sA0h = (_Float16*)smraw;          // layer0 A, hi plane: 9 kk * 512
  _Float16* sA0l = sA0h + 4608;
  _Float16* sA1h = sA0l + 4608;               // layer1 A: 16 kk * 512
  _Float16* sA1l = sA1h + 8192;
  float* sGl  = (float*)(smraw + 51200);      // gates [16][GLP]
  float* sH1  = sGl + 16 * GLP;               // h1 fp32 [16][256] for pred
  float* sWlin = sH1 + ROWS * HID;            // [256]

  const int tid  = threadIdx.x;
  const int lane = tid & 63;
  const int wv   = tid >> 6;                  // wave = pred row
  const int r0   = blockIdx.x * ROWS;

  // epilogue cell mapping: unit eu, rows ef, ef+4, ef+8, ef+12 (bank-spread)
  const int eu = (tid >> 2) & 255;
  const int ef = tid & 3;

  for (int i = tid; i < 3200; i += NTHR) ((int4*)smraw)[i] = make_int4(0, 0, 0, 0);
  if (tid < HID) sWlin[tid] = Wlin[tid];

  const float b0i = bih0[eu]       + bhh0[eu];
  const float b0f = bih0[eu + 256] + bhh0[eu + 256];
  const float b0g = bih0[eu + 512] + bhh0[eu + 512];
  const float b0o = bih0[eu + 768] + bhh0[eu + 768];
  const float b1i = bih1[eu]       + bhh1[eu];
  const float b1f = bih1[eu + 256] + bhh1[eu + 256];
  const float b1g = bih1[eu + 512] + bhh1[eu + 512];
  const float b1o = bih1[eu + 768] + bhh1[eu + 768];
  const float blv = blin[0];
  float c0s[4] = {0.f, 0.f, 0.f, 0.f}, c1s[4] = {0.f, 0.f, 0.f, 0.f};
  __syncthreads();

  for (int t = 0; t < TT; ++t) {
    // ---- pred from h1(t-1) (feeds A0 slot k=0 + out col t-WIN), + x staging ----
    if (t >= WIN) {
      const float4 wl4 = *(const float4*)&sWlin[lane << 2];
      const float4 h4  = *(const float4*)&sH1[(wv << 8) + (lane << 2)];
      float s = wl4.x * h4.x + wl4.y * h4.y + wl4.z * h4.z + wl4.w * h4.w;
      #pragma unroll
      for (int m = 1; m < 64; m <<= 1) s += __shfl_xor(s, m);
      if (lane == 0) {
        const float pv = s + blv;
        out[(size_t)(r0 + wv) * OUTW + (t - WIN)] = pv;
        _Float16 hh, hl; split_f(pv, hh, hl);
        sA0h[wv << 3] = hh; sA0l[wv << 3] = hl;   // aidx(0, wv)
      }
    }
    if (tid < 128) {
      const int r = tid >> 3, f = tid & 7;
      if (f > 0 || t < WIN) {
        const float v = x[((size_t)(r0 + r) * TT + t) * 8 + f];
        _Float16 hh, hl; split_f(v, hh, hl);
        const int ai = r * 8 + f;                  // aidx(f, r), f<8
        sA0h[ai] = hh; sA0l[ai] = hl;
      }
    }
    __syncthreads();

    gate_phase<KK0>(wp, sA0h, sA0l, sGl, wv, lane);          // layer 0
    __syncthreads();

    #pragma unroll
    for (int q = 0; q < 4; ++q) {                            // epilogue 0
      const int r = ef + (q << 2);
      const float gi = sGl[r * GLP + eu]       + b0i;
      const float gf = sGl[r * GLP + eu + 256] + b0f;
      const float gg = sGl[r * GLP + eu + 512] + b0g;
      const float go = sGl[r * GLP + eu + 768] + b0o;
      const float c  = sigm(gf) * c0s[q] + sigm(gi) * tanhx(gg);
      c0s[q] = c;
      const float h = sigm(go) * tanhx(c);
      _Float16 hh, hl; split_f(h, hh, hl);
      const int i1 = aidx(eu, r), i0 = aidx(eu + 8, r);
      sA1h[i1] = hh; sA1l[i1] = hl;     // layer1 input (this step)
      sA0h[i0] = hh; sA0l[i0] = hl;     // layer0 h0prev (next step)
    }
    __syncthreads();

    gate_phase<KK1>(wp + W0H, sA1h, sA1l, sGl, wv, lane);    // layer 1
    __syncthreads();

    #pragma unroll
    for (int q = 0; q < 4; ++q) {                            // epilogue 1
      const int r = ef + (q << 2);
      const float gi = sGl[r * GLP + eu]       + b1i;
      const float gf = sGl[r * GLP + eu + 256] + b1f;
      const float gg = sGl[r * GLP + eu + 512] + b1g;
      const float go = sGl[r * GLP + eu + 768] + b1o;
      const float c  = sigm(gf) * c1s[q] + sigm(gi) * tanhx(gg);
      c1s[q] = c;
      const float h = sigm(go) * tanhx(c);
      _Float16 hh, hl; split_f(h, hh, hl);
      const int i1 = aidx(HID + eu, r);
      sA1h[i1] = hh; sA1l[i1] = hl;     // h1prev (next step)
      sH1[r * HID + eu] = h;            // fp32 h1 for pred
    }
    __syncthreads();
  }

  // ---- final pred (after step 255) -> out col 128 ----
  {
    const float4 wl4 = *(const float4*)&sWlin[lane << 2];
    const float4 h4  = *(const float4*)&sH1[(wv << 8) + (lane << 2)];
    float s = wl4.x * h4.x + wl4.y * h4.y + wl4.z * h4.z + wl4.w * h4.w;
    #pragma unroll
    for (int m = 1; m < 64; m <<= 1) s += __shfl_xor(s, m);
    if (lane == 0) out[(size_t)(r0 + wv) * OUTW + 128] = s + blv;
  }
}

// ---------------------------------------------------------------------------
#define SMEM_BYTES 135424

extern "C" void kernel_launch(void* const* d_in, const int* in_sizes, int n_in,
                              void* d_out, int out_size, void* d_ws, size_t ws_size,
                              hipStream_t stream) {
  (void)in_sizes; (void)n_in; (void)out_size; (void)ws_size;
  const float* x    = (const float*)d_in[0];
  const float* Wih0 = (const float*)d_in[1];
  const float* Whh0 = (const float*)d_in[2];
  const float* bih0 = (const float*)d_in[3];
  const float* bhh0 = (const float*)d_in[4];
  const float* Wih1 = (const float*)d_in[5];
  const float* Whh1 = (const float*)d_in[6];
  const float* bih1 = (const float*)d_in[7];
  const float* bhh1 = (const float*)d_in[8];
  const float* Wlin = (const float*)d_in[9];
  const float* blin = (const float*)d_in[10];
  _Float16* wp = (_Float16*)d_ws;
  float* out = (float*)d_out;

  prep_pack<<<2048, 256, 0, stream>>>(Wih0, Whh0, Wih1, Whh1, wp);

  (void)hipFuncSetAttribute(reinterpret_cast<const void*>(lstm_mfma),
                            hipFuncAttributeMaxDynamicSharedMemorySize, SMEM_BYTES);
  lstm_mfma<<<NBLK, NTHR, SMEM_BYTES, stream>>>(x, bih0, bhh0, bih1, bhh1,
                                                Wlin, blin, wp, out);
}

// Round 5
// 12248.842 us; speedup vs baseline: 3.0188x; 2.4981x over previous
//
#include <hip/hip_runtime.h>
#include <cstdint>

#define HID 256
#define TT 256
#define WIN 128
#define OUTW 129
#define NBLK 64
#define ROWS 16
#define NTHR 1024
#define NKK 25                 // 9 (L0: x+pad kk0, h0 kk1..8) + 16 (L1: h0,h1)
#define NE (NKK * 64 * 512)    // 819200 packed elems per plane

typedef _Float16 half8 __attribute__((ext_vector_type(8)));
typedef _Float16 half4 __attribute__((ext_vector_type(4)));
typedef float f32x4 __attribute__((ext_vector_type(4)));
typedef int i32x4 __attribute__((ext_vector_type(4)));

#define ALO  4.8828125e-4f     // 2^-11  (A lo-plane decode)
#define SLOC 1.5018521e-8f     // 1/(127*16384*32)  (i8*i8 product decode)

__device__ __forceinline__ float sigm(float z)  { return 1.0f / (1.0f + __expf(-z)); }
__device__ __forceinline__ float tanhx(float z) { float e = __expf(2.0f * z); return 1.0f - 2.0f / (e + 1.0f); }

// exact hi/lo fp16 split for A-side values (hi flushed below 2^-10 so lo stays normal)
__device__ __forceinline__ void split_f(float v, _Float16& hi, _Float16& lo) {
  float h = (fabsf(v) < 0.0009765625f) ? 0.0f : (float)(_Float16)v;
  hi = (_Float16)h;
  lo = (_Float16)((v - h) * 2048.0f);
}
__device__ __forceinline__ signed char q8(float v) {
  return (signed char)__float2int_rn(fminf(fmaxf(v * 32.0f, -127.0f), 127.0f));
}

// ---------------------------------------------------------------------------
// prep: pack B into fragment order. hi plane fp16, lo plane i8 (residual*127/2^-14).
// frag(kkG, nt): lane l holds B[k = kkG*32 + (l>>4)*8 + j][n = nt*16 + (l&15)]
// kkG 0: Wih0 (k<8) else 0 | kkG 1..8: Whh0 | kkG 9..24: Wih1 then Whh1
// ---------------------------------------------------------------------------
__global__ void prep_pack(const float* __restrict__ Wih0, const float* __restrict__ Whh0,
                          const float* __restrict__ Wih1, const float* __restrict__ Whh1,
                          _Float16* __restrict__ wpH, signed char* __restrict__ wpI) {
  for (int e = blockIdx.x * blockDim.x + threadIdx.x; e < NE; e += gridDim.x * blockDim.x) {
    const int kkG = e >> 15;
    const int nt = (e >> 9) & 63, l = (e >> 3) & 63, j = e & 7;
    const int kl = ((l >> 4) << 3) + j;
    const int n  = (nt << 4) + (l & 15);
    float w;
    if (kkG == 0)     w = (kl < 8) ? Wih0[n * 8 + kl] : 0.0f;
    else if (kkG < 9) w = Whh0[n * 256 + (kkG - 1) * 32 + kl];
    else {
      const int k = (kkG - 9) * 32 + kl;
      w = (k < 256) ? Wih1[n * 256 + k] : Whh1[n * 256 + (k - 256)];
    }
    const float hi = (fabsf(w) < 6.103515625e-5f) ? 0.0f : (float)(_Float16)w;
    wpH[e] = (_Float16)hi;
    int q = __float2int_rn((w - hi) * 2080768.0f);   // *127/2^-14
    q = q > 127 ? 127 : (q < -127 ? -127 : q);
    wpI[e] = (signed char)q;
  }
}

// ---------------------------------------------------------------------------
// one K=32 chunk: 4 N-tiles (w, w+16, w+32, w+48) x {f16 hi, f16 Alo, i8 resid}
// ---------------------------------------------------------------------------
__device__ __forceinline__ void mfma_kk(
    const _Float16* __restrict__ wpH, const signed char* __restrict__ wpI,
    int kkG, int w, int lane,
    const _Float16* __restrict__ ahp, const _Float16* __restrict__ alp,
    const signed char* __restrict__ aip,
    f32x4 (&accM)[4], f32x4 (&accA)[4], i32x4 (&accI)[4])
{
  const half8 ah = *(const half8*)ahp;
  const half8 al = *(const half8*)alp;
  const long  a8 = *(const long*)aip;
  const size_t b0 = ((size_t)kkG * 64 + w) * 512 + (size_t)lane * 8;
  #pragma unroll
  for (int i = 0; i < 4; ++i) {
    const half8 bh = *(const half8*)(wpH + b0 + (size_t)(i << 4) * 512);
    const long  b8 = *(const long*)(wpI + b0 + (size_t)(i << 4) * 512);
    accM[i] = __builtin_amdgcn_mfma_f32_16x16x32_f16(ah, bh, accM[i], 0, 0, 0);
    accA[i] = __builtin_amdgcn_mfma_f32_16x16x32_f16(al, bh, accA[i], 0, 0, 0);
    accI[i] = __builtin_amdgcn_mfma_i32_16x16x32_i8(a8, b8, accI[i], 0, 0, 0);
  }
}

// ---------------------------------------------------------------------------
// in-register LSTM epilogue: lane owns unit u for gates i,f,g,o; rows (lane>>4)*4+q
// writes h (hi/lo/i8) into the A-region at element offset e0 + 8q
// ---------------------------------------------------------------------------
__device__ __forceinline__ void epi(
    f32x4 (&accM)[4], f32x4 (&accA)[4], i32x4 (&accI)[4],
    float bi, float bf, float bg, float bo, float (&cst)[4],
    _Float16* __restrict__ Ah, _Float16* __restrict__ Al, signed char* __restrict__ Ai,
    int e0)
{
  #pragma unroll
  for (int q = 0; q < 4; ++q) {
    const float gi = accM[0][q] + ALO * accA[0][q] + SLOC * (float)accI[0][q] + bi;
    const float gf = accM[1][q] + ALO * accA[1][q] + SLOC * (float)accI[1][q] + bf;
    const float gg = accM[2][q] + ALO * accA[2][q] + SLOC * (float)accI[2][q] + bg;
    const float go = accM[3][q] + ALO * accA[3][q] + SLOC * (float)accI[3][q] + bo;
    const float c = sigm(gf) * cst[q] + sigm(gi) * tanhx(gg);
    cst[q] = c;
    const float h = sigm(go) * tanhx(c);
    _Float16 hh, hl; split_f(h, hh, hl);
    const int idx = e0 + (q << 3);
    Ah[idx] = hh; Al[idx] = hl; Ai[idx] = q8(h);
  }
}

// ---------------------------------------------------------------------------
// main: 64 blocks x 1024 thr (16 waves), 16 rows/block, weights stream from L2,
// h-state lives in LDS A-fragment form, c-state in registers. 5 barriers/step.
// ---------------------------------------------------------------------------
__global__ __launch_bounds__(NTHR, 4) void lstm_mfma(
    const float* __restrict__ x,
    const float* __restrict__ bih0, const float* __restrict__ bhh0,
    const float* __restrict__ bih1, const float* __restrict__ bhh1,
    const float* __restrict__ Wlin, const float* __restrict__ blin,
    const _Float16* __restrict__ wpH, const signed char* __restrict__ wpI,
    float* __restrict__ out)
{
  // A region: [kk][lane(64)][8]; kk 0..7 = h0, kk 8..15 = h1
  __shared__ __align__(16) _Float16 A1h[8192];
  __shared__ __align__(16) _Float16 A1l[8192];
  __shared__ __align__(16) signed char A1i[8192];
  __shared__ __align__(16) _Float16 A0xh[512];    // layer0 kk=0: 8 x-feats + pad
  __shared__ __align__(16) _Float16 A0xl[512];
  __shared__ __align__(16) signed char A0xi[512];
  __shared__ __align__(16) float sWlin[256];

  const int tid = threadIdx.x, lane = tid & 63, w = tid >> 6;
  const int r0 = blockIdx.x * ROWS;
  const int u = (w << 4) + (lane & 15);           // this lane's hidden unit
  // h-write element base: ((u>>5)*64 + ((u>>3)&3)*16 + (lane>>4)*4)*8 + (u&7)
  const int e0 = (((u >> 5) << 6) + (((u >> 3) & 3) << 4) + (((lane >> 4)) << 2)) * 8 + (u & 7);

  for (int i = tid; i < 8192; i += NTHR) { A1h[i] = (_Float16)0.f; A1l[i] = (_Float16)0.f; A1i[i] = 0; }
  if (tid < 512) { A0xh[tid] = (_Float16)0.f; A0xl[tid] = (_Float16)0.f; A0xi[tid] = 0; }
  if (tid < 256) sWlin[tid] = Wlin[tid];

  const float b0i = bih0[u]       + bhh0[u];
  const float b0f = bih0[u + 256] + bhh0[u + 256];
  const float b0g = bih0[u + 512] + bhh0[u + 512];
  const float b0o = bih0[u + 768] + bhh0[u + 768];
  const float b1i = bih1[u]       + bhh1[u];
  const float b1f = bih1[u + 256] + bhh1[u + 256];
  const float b1g = bih1[u + 512] + bhh1[u + 512];
  const float b1o = bih1[u + 768] + bhh1[u + 768];
  const float blv = blin[0];
  float c0[4] = {0.f, 0.f, 0.f, 0.f}, c1[4] = {0.f, 0.f, 0.f, 0.f};
  __syncthreads();

  for (int t = 0; t < TT; ++t) {
    // ---- A: prediction (wave w = row w) from h1(t-1), + x staging ----
    if (t >= WIN) {
      const int u0 = lane << 2;
      const int pb = ((8 + (u0 >> 5)) * 64 + (((u0 >> 3) & 3) << 4) + w) * 8 + (u0 & 7);
      const half4 h4 = *(const half4*)(A1h + pb);
      const half4 l4 = *(const half4*)(A1l + pb);
      const float4 wl = *(const float4*)(sWlin + u0);
      float s = wl.x * ((float)h4.x + ALO * (float)l4.x)
              + wl.y * ((float)h4.y + ALO * (float)l4.y)
              + wl.z * ((float)h4.z + ALO * (float)l4.z)
              + wl.w * ((float)h4.w + ALO * (float)l4.w);
      #pragma unroll
      for (int m = 1; m < 64; m <<= 1) s += __shfl_xor(s, m);
      if (lane == 0) {
        const float pv = s + blv;
        out[(size_t)(r0 + w) * OUTW + (t - WIN)] = pv;
        _Float16 hh, hl; split_f(pv, hh, hl);
        A0xh[w << 3] = hh; A0xl[w << 3] = hl; A0xi[w << 3] = q8(pv);
      }
    }
    if (tid < 128) {
      const int r = tid >> 3, f = tid & 7;
      if (f > 0 || t < WIN) {
        const float v = x[((size_t)(r0 + r) * TT + t) * 8 + f];
        _Float16 hh, hl; split_f(v, hh, hl);
        A0xh[(r << 3) + f] = hh; A0xl[(r << 3) + f] = hl; A0xi[(r << 3) + f] = q8(v);
      }
    }
    __syncthreads();

    // ---- B: layer-0 gates (K = 32 + 256) ----
    {
      f32x4 z4 = {0.f, 0.f, 0.f, 0.f}; i32x4 zi = {0, 0, 0, 0};
      f32x4 accM[4] = {z4, z4, z4, z4}, accA[4] = {z4, z4, z4, z4};
      i32x4 accI[4] = {zi, zi, zi, zi};
      mfma_kk(wpH, wpI, 0, w, lane,
              A0xh + lane * 8, A0xl + lane * 8, A0xi + lane * 8, accM, accA, accI);
      #pragma unroll 4
      for (int c = 1; c < 9; ++c) {
        const int ao = ((c - 1) * 64 + lane) * 8;
        mfma_kk(wpH, wpI, c, w, lane, A1h + ao, A1l + ao, A1i + ao, accM, accA, accI);
      }
      __syncthreads();                            // all h0(t-1) reads done
      epi(accM, accA, accI, b0i, b0f, b0g, b0o, c0, A1h, A1l, A1i, e0);
    }
    __syncthreads();                              // h0(t) visible

    // ---- C: layer-1 gates (K = 256 h0 + 256 h1) ----
    {
      f32x4 z4 = {0.f, 0.f, 0.f, 0.f}; i32x4 zi = {0, 0, 0, 0};
      f32x4 accM[4] = {z4, z4, z4, z4}, accA[4] = {z4, z4, z4, z4};
      i32x4 accI[4] = {zi, zi, zi, zi};
      #pragma unroll 4
      for (int c = 0; c < 16; ++c) {
        const int ao = (c * 64 + lane) * 8;
        mfma_kk(wpH, wpI, 9 + c, w, lane, A1h + ao, A1l + ao, A1i + ao, accM, accA, accI);
      }
      __syncthreads();                            // all h0/h1 reads done
      epi(accM, accA, accI, b1i, b1f, b1g, b1o, c1, A1h + 4096, A1l + 4096, A1i + 4096, e0);
    }
    __syncthreads();                              // h1(t) visible
  }

  // ---- final prediction from h1(255) -> col 128 ----
  {
    const int u0 = lane << 2;
    const int pb = ((8 + (u0 >> 5)) * 64 + (((u0 >> 3) & 3) << 4) + w) * 8 + (u0 & 7);
    const half4 h4 = *(const half4*)(A1h + pb);
    const half4 l4 = *(const half4*)(A1l + pb);
    const float4 wl = *(const float4*)(sWlin + u0);
    float s = wl.x * ((float)h4.x + ALO * (float)l4.x)
            + wl.y * ((float)h4.y + ALO * (float)l4.y)
            + wl.z * ((float)h4.z + ALO * (float)l4.z)
            + wl.w * ((float)h4.w + ALO * (float)l4.w);
    #pragma unroll
    for (int m = 1; m < 64; m <<= 1) s += __shfl_xor(s, m);
    if (lane == 0) out[(size_t)(r0 + w) * OUTW + 128] = s + blv;
  }
}

// ---------------------------------------------------------------------------
extern "C" void kernel_launch(void* const* d_in, const int* in_sizes, int n_in,
                              void* d_out, int out_size, void* d_ws, size_t ws_size,
                              hipStream_t stream) {
  (void)in_sizes; (void)n_in; (void)out_size; (void)ws_size;
  const float* x    = (const float*)d_in[0];
  const float* Wih0 = (const float*)d_in[1];
  const float* Whh0 = (const float*)d_in[2];
  const float* bih0 = (const float*)d_in[3];
  const float* bhh0 = (const float*)d_in[4];
  const float* Wih1 = (const float*)d_in[5];
  const float* Whh1 = (const float*)d_in[6];
  const float* bih1 = (const float*)d_in[7];
  const float* bhh1 = (const float*)d_in[8];
  const float* Wlin = (const float*)d_in[9];
  const float* blin = (const float*)d_in[10];
  _Float16* wpH   = (_Float16*)d_ws;
  signed char* wpI = (signed char*)d_ws + (size_t)NE * 2;   // after fp16 plane
  float* out = (float*)d_out;

  prep_pack<<<1600, 256, 0, stream>>>(Wih0, Whh0, Wih1, Whh1, wpH, wpI);
  lstm_mfma<<<NBLK, NTHR, 0, stream>>>(x, bih0, bhh0, bih1, bhh1,
                                       Wlin, blin, wpH, wpI, out);
}